// Round 8
// baseline (149.240 us; speedup 1.0000x reference)
//
#include <hip/hip_runtime.h>
#include <hip/hip_bf16.h>

#define BATCH 16
#define CI 64
#define CO 64
#define H 128
#define W 128
#define HO 126
#define WO 126
#define HW (H * W)

typedef short bfrag __attribute__((ext_vector_type(8)));   // 8 bf16 = 4 VGPRs
typedef float ffrag __attribute__((ext_vector_type(4)));   // 4 fp32 acc

typedef __attribute__((address_space(1))) const unsigned char g_byte;
typedef __attribute__((address_space(3))) unsigned char l_byte;

static __device__ __forceinline__ unsigned short f2bf(float f) {
    unsigned u = __float_as_uint(f);
    u += 0x7fffu + ((u >> 16) & 1u);      // RNE
    return (unsigned short)(u >> 16);
}

// Merged prepass (one launch): w -> w_t  and  x -> x_t (bf16, swizzled chunks).
// grid (128, BATCH) x 256 thr; each block owns one (b,row) x-tile + 288 w elems.
// x_t row = 1024 chunks x 16 B; chunk c = col*8 + (o ^ (col&7)) holds ci
// o*8..o*8+7 (low = even ci) of column col — identical to the fused kernel's
// LDS slab layout, so staging is an identity global_load_lds copy.
__global__ void prepass(const float* __restrict__ x, const float* __restrict__ w,
                        unsigned short* __restrict__ x_t, unsigned short* __restrict__ w_t) {
    __shared__ __align__(16) float lf[64 * 132];     // padded fp32 tile
    const int row = blockIdx.x, b = blockIdx.y, t = threadIdx.x;

    // ---- w_t slice: 288 consecutive elements per block (2048*288 = 589824)
    {
        const int base = (b * 128 + row) * 288;
        int i = base + t;
        {
            int ci = i & 63, co = (i >> 6) & 63, bs = i >> 12;
            int bw = bs / 9, s = bs - bw * 9;
            w_t[i] = f2bf(w[(((bw * 64 + co) * 64 + ci) * 9) + s]);
        }
        if (t < 32) {
            i = base + 256 + t;
            int ci = i & 63, co = (i >> 6) & 63, bs = i >> 12;
            int bw = bs / 9, s = bs - bw * 9;
            w_t[i] = f2bf(w[(((bw * 64 + co) * 64 + ci) * 9) + s]);
        }
    }

    // ---- phase 1: coalesced fp32 loads of the x row-tile
    const float* xb = x + (size_t)b * CI * HW + (size_t)row * W;
    {
        const int ci0 = t >> 5, c4 = (t & 31) * 4;
        #pragma unroll
        for (int p = 0; p < 8; ++p) {
            const int ci = p * 8 + ci0;
            *(float4*)&lf[ci * 132 + c4] = *(const float4*)(xb + (size_t)ci * HW + c4);
        }
    }
    __syncthreads();
    // ---- phase 2: pack chunks; consecutive threads -> consecutive 16B writes
    unsigned short* xrow = x_t + ((size_t)(b * 128) + row) * 8192;
    #pragma unroll
    for (int cc = 0; cc < 4; ++cc) {
        const int c = cc * 256 + t;
        const int col = c >> 3, s8 = c & 7, o = s8 ^ (col & 7);
        unsigned int u[4];
        #pragma unroll
        for (int e = 0; e < 4; ++e) {
            __hip_bfloat162 h2 = __float22bfloat162_rn(make_float2(
                lf[(o * 8 + 2 * e) * 132 + col], lf[(o * 8 + 2 * e + 1) * 132 + col]));
            u[e] = *(unsigned int*)&h2;              // low = even ci
        }
        *(uint4*)&xrow[(size_t)c * 8] = *(const uint4*)u;
    }
}

// Ring-pipelined dynconv, 512-thr / 4-waves-per-SIMD (R8 = R7 resubmit after
// infra failure; kernel re-audited: uniform barriers, safe counted vmcnt,
// in-slab global_load_lds addressing):
//  - R6 post-mortem: fused ~38 us with LDS (~6 us) and MFMA (~2.3 us) floors far
//    below -> latency-bound at 2 waves/SIMD.  This version: 8 waves/block
//    (4 co-quarters x 2 col-halves), ring-4 x 16 KB = 64 KB LDS, 2 blocks/CU
//    => 16 waves/CU = 4 waves/SIMD.  Per-thread live set ~105 VGPR (acc 16 +
//    a[] 72) fits the 128 bucket at 4 waves/SIMD — no spill by construction.
//  - ring-4 still gives DISTANCE-2: STAGE(row j+4 -> slab j&3) issues after the
//    lgkm barrier frees slab j&3; first consumed at unit j+2.  The counted wait
//    at unit j only needs row j+3 (issued unit j-1): younger ops =
//    stores(j-1)[16] + loads(j+4)[2] -> vmcnt(18); unit 0 / prologue exact.
//  - x_t is L3-resident (written by prepass) -> staging is latency-cheap; out
//    stores are fire-and-forget and drain under the next unit's compute.
__launch_bounds__(512)
__global__ void dynconv_fused(const unsigned short* __restrict__ x_t,
                              const unsigned short* __restrict__ w_t,
                              const float* __restrict__ bias,
                              float* __restrict__ out) {
    __shared__ __align__(16) unsigned short xs[4 * 8192];   // 4 slabs x 16 KB

    const int tid = threadIdx.x;
    const int gx  = blockIdx.x;              // 0..31 row-ranges
    const int b   = blockIdx.y;
    const int y0  = gx * 4;
    const int nu  = (gx == 31) ? 2 : 4;      // 126 output rows total
    const int rmaxl = nu + 1;                // last real local x-row

    const int wave = tid >> 6, lane = tid & 63;
    const int l16 = lane & 15, lq = lane >> 4;
    const int wq = wave & 3;                 // co quarter (16 co)
    const int wc = wave >> 2;                // col half (64 cols)

    // ---- A-frag preload: all 9 shifts x 2 ks for this wave's co-quarter
    const bfrag* wtb = (const bfrag*)w_t + (size_t)(b * 9) * 512;
    const int co_b = wq * 16 + l16;
    bfrag a[9][2];
    #pragma unroll
    for (int s = 0; s < 9; ++s)
        #pragma unroll
        for (int ks = 0; ks < 2; ++ks)
            a[s][ks] = wtb[s * 512 + co_b * 8 + ks * 4 + lq];

    const float4 bvv4 = *(const float4*)&bias[b * 64 + wq * 16 + lq * 4];

    // x_t base for this (b, y0); row stride = 8192 shorts = 16 KB
    const unsigned short* xtb = x_t + ((size_t)(b * 128) + y0) * 8192;
    const int lnoff = tid * 16;              // byte offset within a row/slab

// stage local row RL into slab SL: 2 x global_load_lds dwordx4 per thread,
// wave-uniform LDS base (slab + wave*1024 + q*8192) + lane*16 — identity copy.
#define STAGE_ROW(RL, SL)                                                       \
    do {                                                                        \
        const char* gsrc_ = (const char*)(xtb + (size_t)(RL) * 8192);           \
        _Pragma("unroll") for (int q_ = 0; q_ < 2; ++q_)                        \
            __builtin_amdgcn_global_load_lds(                                   \
                (g_byte*)(gsrc_ + lnoff + q_ * 8192),                           \
                (l_byte*)((char*)&xs[(SL) * 8192] + wave * 1024 + q_ * 8192),   \
                16, 0, 0);                                                      \
    } while (0)

    __builtin_amdgcn_sched_barrier(0);       // A/bias loads issued before staging

    // ---- prologue: rows 0..3 -> slabs 0..3
    #pragma unroll
    for (int r = 0; r < 4; ++r) STAGE_ROW(r, r);
    asm volatile("s_waitcnt vmcnt(2)" ::: "memory");    // rows 0..2 landed
    __builtin_amdgcn_s_barrier();
    __builtin_amdgcn_sched_barrier(0);

    for (int j = 0; j < nu; ++j) {
        // 1. compute row j from slabs (j..j+2)&3 — pure ds_read + MFMA
        ffrag acc[4];
        #pragma unroll
        for (int nt = 0; nt < 4; ++nt) acc[nt] = (ffrag){0.f, 0.f, 0.f, 0.f};

        #pragma unroll
        for (int s = 0; s < 9; ++s) {
            const int dy = s / 3, dx = s - dy * 3;
            const unsigned short* slabp = &xs[((j + dy) & 3) * 8192];
            #pragma unroll
            for (int ks = 0; ks < 2; ++ks) {
                const int o = ks * 4 + lq;
                #pragma unroll
                for (int nt = 0; nt < 4; ++nt) {
                    int colx = wc * 64 + nt * 16 + l16 + dx;
                    if (colx > 127) colx = 127;    // clamped lanes -> discarded cols
                    const bfrag bf = *(const bfrag*)&slabp[(colx * 8 + (o ^ (colx & 7))) * 8];
                    acc[nt] = __builtin_amdgcn_mfma_f32_16x16x32_bf16(a[s][ks], bf, acc[nt], 0, 0, 0);
                }
            }
        }

        // 2. all waves' reads of slab j&3 done -> slab reusable
        asm volatile("s_waitcnt lgkmcnt(0)" ::: "memory");
        __builtin_amdgcn_s_barrier();
        __builtin_amdgcn_sched_barrier(0);

        // 3. issue loads for row j+4 into the freed slab (clamped dups -> dead)
        {
            const int rl = (j + 4 <= rmaxl) ? (j + 4) : rmaxl;
            STAGE_ROW(rl, j & 3);
        }
        __builtin_amdgcn_sched_barrier(0);

        // 4. counted wait: row j+3 landed (younger = stores(j-1)[16] +
        //    loads(j+4)[2]); unit 0 has no stores yet -> exact vmcnt(2).
        if (j == 0) { asm volatile("s_waitcnt vmcnt(2)"  ::: "memory"); }
        else        { asm volatile("s_waitcnt vmcnt(18)" ::: "memory"); }
        __builtin_amdgcn_s_barrier();
        __builtin_amdgcn_sched_barrier(0);

        // 5. stores row j (16 predicated dwords/thread) — drain lazily
        const int oy = y0 + j;
        #pragma unroll
        for (int r = 0; r < 4; ++r) {
            float* op = out + ((size_t)(b * 64 + wq * 16 + lq * 4 + r) * HO + oy) * WO;
            const float bvv = ((const float*)&bvv4)[r];
            #pragma unroll
            for (int nt = 0; nt < 4; ++nt) {
                const int ox = wc * 64 + nt * 16 + l16;
                if (ox < WO) op[ox] = acc[nt][r] + bvv;
            }
        }
    }
#undef STAGE_ROW
}

extern "C" void kernel_launch(void* const* d_in, const int* in_sizes, int n_in,
                              void* d_out, int out_size, void* d_ws, size_t ws_size,
                              hipStream_t stream) {
    const float* x    = (const float*)d_in[0];
    const float* w    = (const float*)d_in[1];
    const float* bias = (const float*)d_in[2];
    float* out        = (float*)d_out;

    unsigned short* w_t = (unsigned short*)d_ws;                       // 1,179,648 B
    unsigned short* x_t = (unsigned short*)((char*)d_ws + 1179648);    // 33,554,432 B

    prepass<<<dim3(128, BATCH), dim3(256), 0, stream>>>(x, w, x_t, w_t);
    dynconv_fused<<<dim3(32, BATCH), dim3(512), 0, stream>>>(x_t, w_t, bias, out);
}